// Round 1
// 270.787 us; speedup vs baseline: 1.1550x; 1.1550x over previous
//
#include <hip/hip_runtime.h>

// StrokeField R7: carry contracted coords THROUGH the two-level sort.
// R6 post-mortem: kF fetched 133MB (vs 38MB ideal) because it gathered
// cw[3*idx] (12B scattered over 24MB) per point; kD used only 64 blocks.
// R7: kC scatters float4(cw, idx|sub<<21) into supercell runs (contiguous,
// clean writes); kD (256 blocks, 4/supercell on the SAME XCD via
// blockIdx=g*64+s so partial lines merge in one L2) forwards float4s into
// 64-aligned cell chunks; kF reads sortedPts coalesced -- no gather, no
// idxFinal, no 9.5MB memset. Cell histogram moved into kC (16KB LDS),
// global chunk-aligned cell scan in a 1-block kernel, chunkInfo (with
// packed per-chunk count) generated by kD's g==0 blocks.
// R6 path kept verbatim as fallback tier if ws too small.

#define NC_DIM 16
#define NC (NC_DIM * NC_DIM * NC_DIM)   // 4096 cells = 64 supercells x 64 sub
#define MAXS 512
#define CELL_INV 8.0f

typedef unsigned short u16;
typedef unsigned long long u64;

__device__ __forceinline__ void contract_pt(float x, float y, float z,
                                            float& cx, float& cy, float& cz) {
    float n2 = fmaf(x, x, fmaf(y, y, z * z));
    float nn = fmaxf(__builtin_amdgcn_sqrtf(n2), 1e-9f);
    float invn = 1.0f / nn;
    float scl = (nn <= 1.0f) ? 0.5f : (2.0f - invn) * (0.5f * invn);
    cx = x * scl; cy = y * scl; cz = z * scl;
}

__device__ __forceinline__ int cid_of(float cx, float cy, float cz) {
    int ix = (int)floorf((cx + 1.0f) * CELL_INV);
    int iy = (int)floorf((cy + 1.0f) * CELL_INV);
    int iz = (int)floorf((cz + 1.0f) * CELL_INV);
    ix = min(max(ix, 0), 15); iy = min(max(iy, 0), 15); iz = min(max(iz, 0), 15);
    return ix | (iy << 4) | (iz << 8);
}
__device__ __forceinline__ int sid_of(int cid) {   // supercell 0..63
    return ((cid >> 2) & 3) | (((cid >> 6) & 3) << 2) | (((cid >> 10) & 3) << 4);
}
__device__ __forceinline__ int sub_of(int cid) {   // subcell 0..63
    return (cid & 3) | (((cid >> 4) & 3) << 2) | (((cid >> 8) & 3) << 4);
}
__device__ __forceinline__ int cid_from(int s, int t) {
    int ix = (((s) & 3) << 2) | (t & 3);
    int iy = (((s >> 2) & 3) << 2) | ((t >> 2) & 3);
    int iz = (((s >> 4) & 3) << 2) | ((t >> 4) & 3);
    return ix | (iy << 4) | (iz << 8);
}

// KA: contract, write cw to out, supercell histogram (LDS-aggregated).
// (shared by R7 and R6 tiers)
__global__ __launch_bounds__(256) void kA(
    const float* __restrict__ coords, float* __restrict__ out,
    int* __restrict__ superCnt, int n)
{
    __shared__ int h[64];
    if (threadIdx.x < 64) h[threadIdx.x] = 0;
    __syncthreads();
    float* cw = out + 4 * (size_t)n;
    int base = blockIdx.x * 1024 + threadIdx.x;
#pragma unroll
    for (int k = 0; k < 4; ++k) {
        int i = base + k * 256;
        if (i < n) {
            float cx, cy, cz;
            contract_pt(coords[3 * i], coords[3 * i + 1], coords[3 * i + 2], cx, cy, cz);
            cw[3 * i] = cx; cw[3 * i + 1] = cy; cw[3 * i + 2] = cz;
            atomicAdd(&h[sid_of(cid_of(cx, cy, cz))], 1);
        }
    }
    __syncthreads();
    if (threadIdx.x < 64 && h[threadIdx.x])
        atomicAdd(&superCnt[threadIdx.x], h[threadIdx.x]);
}

// KE: per-cell ordered stroke sublist (AABB vs sphere, exact-zero margin).
// (shared by R7 and R6 tiers)
__global__ __launch_bounds__(256) void kE(
    const float* __restrict__ shape, u16* __restrict__ cellList,
    int ns)
{
    int wave = (blockIdx.x * blockDim.x + threadIdx.x) >> 6;
    int lane = threadIdx.x & 63;
    if (wave >= NC) return;
    int ix = wave & 15, iy = (wave >> 4) & 15, iz = wave >> 8;
    float lox = -1.0f + ix * 0.125f, hix = lox + 0.125f;
    float loy = -1.0f + iy * 0.125f, hiy = loy + 0.125f;
    float loz = -1.0f + iz * 0.125f, hiz = loz + 0.125f;
    int cnt = 0;
    u16* lst = cellList + (size_t)wave * MAXS;
    for (int base = 0; base < ns; base += 64) {
        int s = base + lane;
        bool pass = false;
        if (s < ns) {
            float4 sp = ((const float4*)shape)[s];
            float dx = sp.x - fminf(fmaxf(sp.x, lox), hix);
            float dy = sp.y - fminf(fmaxf(sp.y, loy), hiy);
            float dz = sp.z - fminf(fmaxf(sp.z, loz), hiz);
            float d2 = fmaf(dx, dx, fmaf(dy, dy, dz * dz));
            float rr = sp.w + 0.101f;
            pass = d2 <= rr * rr;
        }
        u64 m = __ballot(pass);
        if (pass) lst[cnt + __popcll(m & ((1ull << lane) - 1ull))] = (u16)s;
        cnt += __popcll(m);
    }
    if (lane == 0) ((int*)(cellList + (size_t)NC * MAXS))[wave] = cnt;
}

// ============================ R7 tier ============================

// KB7: 64-wide exact scan of supercell counts (element units).
__global__ __launch_bounds__(64) void kB7(
    const int* __restrict__ superCnt, int* __restrict__ superBase,
    int* __restrict__ superCursor)
{
    int t = threadIdx.x;
    int cnt = superCnt[t];
    int v = cnt;
    for (int off = 1; off < 64; off <<= 1) {
        int u = __shfl_up(v, off, 64);
        if (t >= off) v += u;
    }
    int excl = v - cnt;
    superBase[t] = excl;
    superCursor[t] = excl;
}

// KC7: block-aggregated scatter of float4(cw, idx|sub<<21) into supercell
// runs (contiguous per block -> clean line writes) + 4096-cell histogram.
__global__ __launch_bounds__(256) void kC7(
    const float* __restrict__ out, int* __restrict__ superCursor,
    int* __restrict__ cellCnt, float4* __restrict__ sortedTmp, int n)
{
    __shared__ int scnt[64], sbase[64];
    __shared__ int chist[NC];                       // 16KB
    for (int t = threadIdx.x; t < NC; t += 256) chist[t] = 0;
    if (threadIdx.x < 64) scnt[threadIdx.x] = 0;
    __syncthreads();
    const float* cw = out + 4 * (size_t)n;
    int base = blockIdx.x * 2048 + threadIdx.x;
    float cx[8], cy[8], cz[8];
    int cid[8], sid[8];
#pragma unroll
    for (int k = 0; k < 8; ++k) {
        int i = base + k * 256;
        if (i < n) {
            cx[k] = cw[3 * i]; cy[k] = cw[3 * i + 1]; cz[k] = cw[3 * i + 2];
            int c = cid_of(cx[k], cy[k], cz[k]);
            cid[k] = c; sid[k] = sid_of(c);
            atomicAdd(&scnt[sid[k]], 1);
            atomicAdd(&chist[c], 1);
        } else sid[k] = -1;
    }
    __syncthreads();
    if (threadIdx.x < 64) {
        int c = scnt[threadIdx.x];
        sbase[threadIdx.x] = c ? atomicAdd(&superCursor[threadIdx.x], c) : 0;
        scnt[threadIdx.x] = 0;
    }
    __syncthreads();
#pragma unroll
    for (int k = 0; k < 8; ++k) {
        if (sid[k] >= 0) {
            int i = base + k * 256;
            int r = atomicAdd(&scnt[sid[k]], 1);
            sortedTmp[sbase[sid[k]] + r] = make_float4(
                cx[k], cy[k], cz[k],
                __int_as_float(i | (sub_of(cid[k]) << 21)));
        }
    }
    __syncthreads();
    for (int t = threadIdx.x; t < NC; t += 256) {
        int v = chist[t];
        if (v) atomicAdd(&cellCnt[t], v);
    }
}

// KS7: global chunk-aligned scan over 4096 cells in supercell-major order.
__global__ __launch_bounds__(1024) void kS7(
    const int* __restrict__ cellCnt, int* __restrict__ cellSlotStart,
    int* __restrict__ cellCursor, int* __restrict__ cellChunkBase)
{
    __shared__ int tsum[1024];
    int t = threadIdx.x;
    int ch[4], cidv[4];
    int loc = 0;
#pragma unroll
    for (int q = 0; q < 4; ++q) {
        int k = t * 4 + q;                    // supercell-major cell order
        int cid = cid_from(k >> 6, k & 63);
        cidv[q] = cid;
        int c = cellCnt[cid];
        ch[q] = (c + 63) >> 6;
        loc += ch[q];
    }
    tsum[t] = loc;
    __syncthreads();
    for (int off = 1; off < 1024; off <<= 1) {
        int u = (t >= off) ? tsum[t - off] : 0;
        __syncthreads();
        tsum[t] += u;
        __syncthreads();
    }
    int excl = tsum[t] - loc;
#pragma unroll
    for (int q = 0; q < 4; ++q) {
        cellChunkBase[cidv[q]] = excl;
        cellSlotStart[cidv[q]] = excl << 6;
        cellCursor[cidv[q]]   = excl << 6;
        excl += ch[q];
    }
}

// KD7: 4 blocks per supercell (blockIdx = g*64+s keeps all 4 on one XCD:
// blockIdx%8 == s%8), forward float4s into 64-aligned cell chunks.
// g==0 blocks also emit chunkInfo = (cid | cntInChunk<<16, slotBase).
__global__ __launch_bounds__(1024) void kD7(
    const int* __restrict__ superCnt, const int* __restrict__ superBase,
    const float4* __restrict__ sortedTmp, float4* __restrict__ sortedPts,
    int* __restrict__ cellCursor, const int* __restrict__ cellCnt,
    const int* __restrict__ cellSlotStart, const int* __restrict__ cellChunkBase,
    int2* __restrict__ chunkInfo)
{
    __shared__ int cnt64[64], gbase[64];
    int s = blockIdx.x & 63, g = blockIdx.x >> 6;
    int t = threadIdx.x;
    if (t < 64) cnt64[t] = 0;
    if (g == 0 && t < 64) {
        int cid = cid_from(s, t);
        int c = cellCnt[cid];
        int cb = cellChunkBase[cid];
        int ss = cellSlotStart[cid];
        int nch = (c + 63) >> 6;
        for (int q = 0; q < nch; ++q) {
            int rem = c - (q << 6); rem = rem > 64 ? 64 : rem;
            chunkInfo[cb + q] = make_int2(cid | (rem << 16), ss + (q << 6));
        }
    }
    __syncthreads();
    int cnt = superCnt[s];
    int rb = superBase[s];
    int q0 = (int)(((long long)cnt * g) >> 2);
    int q1 = (int)(((long long)cnt * (g + 1)) >> 2);
    for (int j = q0 + t; j < q1; j += 1024) {
        int bits = __float_as_int(sortedTmp[rb + j].w);
        atomicAdd(&cnt64[(bits >> 21) & 63], 1);
    }
    __syncthreads();
    if (t < 64) {
        int c = cnt64[t];
        gbase[t] = c ? atomicAdd(&cellCursor[cid_from(s, t)], c) : 0;
        cnt64[t] = 0;
    }
    __syncthreads();
    for (int j = q0 + t; j < q1; j += 1024) {
        float4 p = sortedTmp[rb + j];
        int bits = __float_as_int(p.w);
        int sub = (bits >> 21) & 63;
        int r = atomicAdd(&cnt64[sub], 1);
        p.w = __int_as_float(bits & 0x1FFFFF);
        sortedPts[gbase[sub] + r] = p;
    }
}

// KF7: one wave per chunk; coalesced float4 point reads (coords + idx).
__global__ __launch_bounds__(256) void kF7(
    const float* __restrict__ shape, const float* __restrict__ color,
    const float* __restrict__ alpha,
    const int2* __restrict__ chunkInfo, const float4* __restrict__ sortedPts,
    const u16* __restrict__ cellList, const int* __restrict__ strokeCnt,
    float* __restrict__ out, int n, int ns, int maxChunks)
{
    __shared__ float4 sA[MAXS];   // (ax, ay, az, K = 0.5 - 5r)
    __shared__ float4 sB[MAXS];   // (dp, cr, cg, cb)
    for (int s = threadIdx.x; s < ns; s += blockDim.x) {
        float4 sp = ((const float4*)shape)[s];
        sA[s] = make_float4(sp.x, sp.y, sp.z, fmaf(-5.0f, sp.w, 0.5f));
        sB[s] = make_float4(fmaxf(alpha[s], 0.0f) * 50.0f,
                            color[3 * s], color[3 * s + 1], color[3 * s + 2]);
    }
    __syncthreads();

    int k = blockIdx.x * 4 + (threadIdx.x >> 6);
    int lane = threadIdx.x & 63;
    if (k >= maxChunks) return;
    int2 info = chunkInfo[k];
    if (info.x < 0) return;
    int cell = info.x & 0xFFF;
    int cnum = info.x >> 16;

    float4 pt = sortedPts[info.y + lane];
    bool valid = lane < cnum;
    int idx = __float_as_int(pt.w) & 0x1FFFFF;
    float cx = valid ? pt.x : 1e9f;
    float cy = valid ? pt.y : 1e9f;
    float cz = valid ? pt.z : 1e9f;

    int nl = strokeCnt[cell];
    const u16* lst = cellList + (size_t)cell * MAXS;

    float T = 1.0f, Ad = 0.0f, Ar = 0.0f, Ag = 0.0f, Ab = 0.0f;
    for (int jb = (((nl + 63) >> 6) << 6) - 64; jb >= 0; jb -= 64) {
        int jl = jb + lane;
        int myId = (jl < nl) ? (int)lst[jl] : 0;
        int hi = nl - jb; hi = hi > 64 ? 64 : hi;
        int sid = __builtin_amdgcn_readlane(myId, hi - 1);
        float4 a = sA[sid];
        float4 b = sB[sid];
        for (int jj = hi - 1; jj >= 0; --jj) {
            int sidn = __builtin_amdgcn_readlane(myId, jj > 0 ? jj - 1 : 0);
            float4 an = sA[sidn];
            float4 bn = sB[sidn];
            float dx = cx - a.x, dy = cy - a.y, dz = cz - a.z;
            float d2 = fmaf(dx, dx, fmaf(dy, dy, dz * dz));
            float dist = __builtin_amdgcn_sqrtf(d2);
            float omt = fminf(fmaxf(fmaf(5.0f, dist, a.w), 0.0f), 1.0f);
            float Tn = omt * T;
            float tT = T - Tn;
            Ad = fmaf(tT, b.x, Ad);
            Ar = fmaf(tT, b.y, Ar);
            Ag = fmaf(tT, b.z, Ag);
            Ab = fmaf(tT, b.w, Ab);
            T = Tn;
            a = an; b = bn;
        }
    }

    if (valid) {
        float inv = 1.0f / (1.0f + 1e-6f - T);
        out[idx] = Ad;
        float* rgb = out + n;
        rgb[3 * idx]     = fminf(fmaxf(Ar * inv, 0.0f), 1.0f);
        rgb[3 * idx + 1] = fminf(fmaxf(Ag * inv, 0.0f), 1.0f);
        rgb[3 * idx + 2] = fminf(fmaxf(Ab * inv, 0.0f), 1.0f);
    }
}

// ============================ R6 tier (verified fallback) ============================

__global__ __launch_bounds__(64) void kB(
    const int* __restrict__ superCnt, int* __restrict__ superChunkBase,
    int* __restrict__ superCursor)
{
    int t = threadIdx.x;
    int cnt = superCnt[t];
    int cap = ((cnt + 63) >> 6) + 65;
    int v = cap;
    for (int off = 1; off < 64; off <<= 1) {
        int u = __shfl_up(v, off, 64);
        if (t >= off) v += u;
    }
    int excl = v - cap;
    superChunkBase[t] = excl;
    superCursor[t] = excl << 6;
}

__global__ __launch_bounds__(256) void kC(
    const float* __restrict__ out, int* __restrict__ superCursor,
    int2* __restrict__ idxTmp, int n)
{
    __shared__ int scnt[64], sbase[64];
    if (threadIdx.x < 64) scnt[threadIdx.x] = 0;
    __syncthreads();
    const float* cw = out + 4 * (size_t)n;
    int base = blockIdx.x * 2048 + threadIdx.x;
    int sid[8], cid[8];
#pragma unroll
    for (int k = 0; k < 8; ++k) {
        int i = base + k * 256;
        if (i < n) {
            int c = cid_of(cw[3 * i], cw[3 * i + 1], cw[3 * i + 2]);
            cid[k] = c; sid[k] = sid_of(c);
            atomicAdd(&scnt[sid[k]], 1);
        } else sid[k] = -1;
    }
    __syncthreads();
    if (threadIdx.x < 64) {
        int c = scnt[threadIdx.x];
        sbase[threadIdx.x] = c ? atomicAdd(&superCursor[threadIdx.x], c) : 0;
        scnt[threadIdx.x] = 0;
    }
    __syncthreads();
#pragma unroll
    for (int k = 0; k < 8; ++k) {
        if (sid[k] >= 0) {
            int i = base + k * 256;
            int r = atomicAdd(&scnt[sid[k]], 1);
            idxTmp[sbase[sid[k]] + r] = make_int2(i, cid[k]);
        }
    }
}

__global__ __launch_bounds__(1024) void kD(
    const int* __restrict__ superCnt, const int* __restrict__ superChunkBase,
    const int2* __restrict__ idxTmp, int* __restrict__ idxFinal,
    int2* __restrict__ chunkInfo, int* __restrict__ cellCnt)
{
    __shared__ int cnt64[64], cur[64];
    int s = blockIdx.x, t = threadIdx.x;
    if (t < 64) cnt64[t] = 0;
    __syncthreads();
    int cntS = superCnt[s];
    int cb = superChunkBase[s];
    int slotBase = cb << 6;
    for (int j = t; j < cntS; j += 1024)
        atomicAdd(&cnt64[sub_of(idxTmp[slotBase + j].y)], 1);
    __syncthreads();
    if (t < 64) {
        int c = cnt64[t];
        int ch = (c + 63) >> 6;
        int v = ch;
        for (int off = 1; off < 64; off <<= 1) {
            int u = __shfl_up(v, off, 64);
            if (t >= off) v += u;
        }
        int chOff = v - ch;
        int st = chOff << 6;
        cur[t] = st;
        int cid = cid_from(s, t);
        cellCnt[cid] = c;
        for (int q = 0; q < ch; ++q)
            chunkInfo[cb + chOff + q] = make_int2(cid, slotBase + st + (q << 6));
    }
    __syncthreads();
    for (int j = t; j < cntS; j += 1024) {
        int2 r = idxTmp[slotBase + j];
        int pos = atomicAdd(&cur[sub_of(r.y)], 1);
        idxFinal[slotBase + pos] = r.x;
    }
}

__global__ __launch_bounds__(256) void kF(
    const float* __restrict__ shape, const float* __restrict__ color,
    const float* __restrict__ alpha,
    const int2* __restrict__ chunkInfo, const int* __restrict__ idxFinal,
    const u16* __restrict__ cellList, const int* __restrict__ strokeCnt,
    float* __restrict__ out, int n, int ns, int maxChunks)
{
    __shared__ float4 sA[MAXS];
    __shared__ float4 sB[MAXS];
    for (int s = threadIdx.x; s < ns; s += blockDim.x) {
        float4 sp = ((const float4*)shape)[s];
        sA[s] = make_float4(sp.x, sp.y, sp.z, fmaf(-5.0f, sp.w, 0.5f));
        sB[s] = make_float4(fmaxf(alpha[s], 0.0f) * 50.0f,
                            color[3 * s], color[3 * s + 1], color[3 * s + 2]);
    }
    __syncthreads();

    int k = blockIdx.x * 4 + (threadIdx.x >> 6);
    int lane = threadIdx.x & 63;
    if (k >= maxChunks) return;
    int2 info = chunkInfo[k];
    int cell = info.x;
    if (cell < 0) return;

    int idx = idxFinal[info.y + lane];
    bool valid = idx >= 0;
    const float* cw = out + 4 * (size_t)n;
    float cx = 1e9f, cy = 1e9f, cz = 1e9f;
    if (valid) { cx = cw[3 * idx]; cy = cw[3 * idx + 1]; cz = cw[3 * idx + 2]; }

    int nl = strokeCnt[cell];
    const u16* lst = cellList + (size_t)cell * MAXS;

    float T = 1.0f, Ad = 0.0f, Ar = 0.0f, Ag = 0.0f, Ab = 0.0f;
    for (int jb = (((nl + 63) >> 6) << 6) - 64; jb >= 0; jb -= 64) {
        int jl = jb + lane;
        int myId = (jl < nl) ? (int)lst[jl] : 0;
        int hi = nl - jb; hi = hi > 64 ? 64 : hi;
        int sid = __builtin_amdgcn_readlane(myId, hi - 1);
        float4 a = sA[sid];
        float4 b = sB[sid];
        for (int jj = hi - 1; jj >= 0; --jj) {
            int sidn = __builtin_amdgcn_readlane(myId, jj > 0 ? jj - 1 : 0);
            float4 an = sA[sidn];
            float4 bn = sB[sidn];
            float dx = cx - a.x, dy = cy - a.y, dz = cz - a.z;
            float d2 = fmaf(dx, dx, fmaf(dy, dy, dz * dz));
            float dist = __builtin_amdgcn_sqrtf(d2);
            float omt = fminf(fmaxf(fmaf(5.0f, dist, a.w), 0.0f), 1.0f);
            float Tn = omt * T;
            float tT = T - Tn;
            Ad = fmaf(tT, b.x, Ad);
            Ar = fmaf(tT, b.y, Ar);
            Ag = fmaf(tT, b.z, Ag);
            Ab = fmaf(tT, b.w, Ab);
            T = Tn;
            a = an; b = bn;
        }
    }

    if (valid) {
        float inv = 1.0f / (1.0f + 1e-6f - T);
        out[idx] = Ad;
        float* rgb = out + n;
        rgb[3 * idx]     = fminf(fmaxf(Ar * inv, 0.0f), 1.0f);
        rgb[3 * idx + 1] = fminf(fmaxf(Ag * inv, 0.0f), 1.0f);
        rgb[3 * idx + 2] = fminf(fmaxf(Ab * inv, 0.0f), 1.0f);
    }
}

// ---- Fallback: R4 direct kernel ----
#define PTS 4
__global__ __launch_bounds__(256) void stroke_direct(
    const float* __restrict__ coords, const float* __restrict__ shape,
    const float* __restrict__ color, const float* __restrict__ alpha,
    float* __restrict__ out, int n, int ns)
{
    __shared__ float4 fA[MAXS + 1];
    __shared__ float4 fB[MAXS + 1];
    for (int s = threadIdx.x; s < ns; s += blockDim.x) {
        float4 sp = ((const float4*)shape)[s];
        fA[s + 1] = make_float4(sp.x, sp.y, sp.z, fmaf(-5.0f, sp.w, 0.5f));
        fB[s + 1] = make_float4(fmaxf(alpha[s], 0.0f) * 50.0f,
                                color[3 * s], color[3 * s + 1], color[3 * s + 2]);
    }
    __syncthreads();
    const int base = blockIdx.x * (blockDim.x * PTS) + threadIdx.x;
    float cx[PTS], cy[PTS], cz[PTS], T[PTS], Ad[PTS], Ar[PTS], Ag[PTS], Ab[PTS];
#pragma unroll
    for (int k = 0; k < PTS; ++k) {
        int i = base + k * 256; i = (i < n) ? i : (n - 1);
        contract_pt(coords[3 * i], coords[3 * i + 1], coords[3 * i + 2],
                    cx[k], cy[k], cz[k]);
        T[k] = 1.0f; Ad[k] = Ar[k] = Ag[k] = Ab[k] = 0.0f;
    }
    float4 a = fA[ns], b = fB[ns];
#pragma unroll 2
    for (int s = ns - 1; s >= 0; --s) {
        float4 an = fA[s], bn = fB[s];
#pragma unroll
        for (int k = 0; k < PTS; ++k) {
            float dx = cx[k] - a.x, dy = cy[k] - a.y, dz = cz[k] - a.z;
            float d2 = fmaf(dx, dx, fmaf(dy, dy, dz * dz));
            float dist = __builtin_amdgcn_sqrtf(d2);
            float omt = fminf(fmaxf(fmaf(5.0f, dist, a.w), 0.0f), 1.0f);
            float Tn = omt * T[k];
            float tT = T[k] - Tn;
            Ad[k] = fmaf(tT, b.x, Ad[k]); Ar[k] = fmaf(tT, b.y, Ar[k]);
            Ag[k] = fmaf(tT, b.z, Ag[k]); Ab[k] = fmaf(tT, b.w, Ab[k]);
            T[k] = Tn;
        }
        a = an; b = bn;
    }
    float* rgb = out + n;
    float* cw  = out + 4 * (size_t)n;
#pragma unroll
    for (int k = 0; k < PTS; ++k) {
        int i = base + k * 256;
        if (i >= n) break;
        float inv = 1.0f / (1.0f + 1e-6f - T[k]);
        out[i] = Ad[k];
        rgb[3 * i]     = fminf(fmaxf(Ar[k] * inv, 0.0f), 1.0f);
        rgb[3 * i + 1] = fminf(fmaxf(Ag[k] * inv, 0.0f), 1.0f);
        rgb[3 * i + 2] = fminf(fmaxf(Ab[k] * inv, 0.0f), 1.0f);
        cw[3 * i]     = cx[k];
        cw[3 * i + 1] = cy[k];
        cw[3 * i + 2] = cz[k];
    }
}

extern "C" void kernel_launch(void* const* d_in, const int* in_sizes, int n_in,
                              void* d_out, int out_size, void* d_ws, size_t ws_size,
                              hipStream_t stream) {
    const float* coords = (const float*)d_in[0];
    const float* shape  = (const float*)d_in[1];
    const float* color  = (const float*)d_in[2];
    const float* alpha  = (const float*)d_in[3];
    float* out = (float*)d_out;

    int n  = in_sizes[0] / 3;
    int ns = in_sizes[1] / 4;

    auto al = [](size_t v) { return (v + 255) & ~(size_t)255; };

    // ---- R7 layout ----
    int maxChunks7 = (n + 63) / 64 + NC;
    size_t o7_superCnt  = 0;                                   // 256 B
    size_t o7_cellCnt   = 256;                                 // NC*4
    size_t o7_superBase = al(256 + (size_t)NC * 4);            // 256 B
    size_t o7_superCur  = o7_superBase + 256;                  // 256 B
    size_t o7_cellStart = al(o7_superCur + 256);               // NC*4
    size_t o7_cellCur   = o7_cellStart + (size_t)NC * 4;       // NC*4
    size_t o7_cellCB    = o7_cellCur + (size_t)NC * 4;         // NC*4
    size_t o7_chunk     = al(o7_cellCB + (size_t)NC * 4);
    size_t o7_list      = al(o7_chunk + (size_t)maxChunks7 * 8);
    size_t o7_tmp       = al(o7_list + (size_t)NC * MAXS * 2 + NC * 4);
    size_t o7_pts       = al(o7_tmp + (size_t)n * 16);
    size_t need7        = o7_pts + (size_t)maxChunks7 * 64 * 16;

    // ---- R6 layout ----
    int maxChunks6 = (n + 63) / 64 + 4224;
    size_t nslots6 = (size_t)maxChunks6 * 64;
    size_t o6_cellCnt = 768;
    size_t o6_chunk   = al(o6_cellCnt + NC * 4);
    size_t o6_list    = al(o6_chunk + (size_t)maxChunks6 * 8);
    size_t o6_tmp     = al(o6_list + (size_t)NC * MAXS * 2 + NC * 4);
    size_t o6_final   = al(o6_tmp + nslots6 * 8);
    size_t need6      = o6_final + nslots6 * 4;

    if (ws_size >= need7 && ns <= MAXS && n >= 1 && n <= (1 << 21)) {
        char* w = (char*)d_ws;
        int*    superCnt  = (int*)(w + o7_superCnt);
        int*    cellCnt   = (int*)(w + o7_cellCnt);
        int*    superBase = (int*)(w + o7_superBase);
        int*    superCur  = (int*)(w + o7_superCur);
        int*    cellStart = (int*)(w + o7_cellStart);
        int*    cellCur   = (int*)(w + o7_cellCur);
        int*    cellCB    = (int*)(w + o7_cellCB);
        int2*   chunkInfo = (int2*)(w + o7_chunk);
        u16*    cellList  = (u16*)(w + o7_list);
        int*    strokeCnt = (int*)(w + o7_list + (size_t)NC * MAXS * 2);
        float4* sortedTmp = (float4*)(w + o7_tmp);
        float4* sortedPts = (float4*)(w + o7_pts);

        hipMemsetAsync(w, 0, 256 + (size_t)NC * 4, stream);           // superCnt+cellCnt
        hipMemsetAsync(chunkInfo, 0xFF, (size_t)maxChunks7 * 8, stream);

        kA<<<(n + 1023) / 1024, 256, 0, stream>>>(coords, out, superCnt, n);
        kB7<<<1, 64, 0, stream>>>(superCnt, superBase, superCur);
        kC7<<<(n + 2047) / 2048, 256, 0, stream>>>(out, superCur, cellCnt, sortedTmp, n);
        kS7<<<1, 1024, 0, stream>>>(cellCnt, cellStart, cellCur, cellCB);
        kD7<<<256, 1024, 0, stream>>>(superCnt, superBase, sortedTmp, sortedPts,
                                      cellCur, cellCnt, cellStart, cellCB, chunkInfo);
        kE<<<(NC * 64) / 256, 256, 0, stream>>>(shape, cellList, ns);
        kF7<<<(maxChunks7 + 3) / 4, 256, 0, stream>>>(
            shape, color, alpha, chunkInfo, sortedPts, cellList, strokeCnt,
            out, n, ns, maxChunks7);
    } else if (ws_size >= need6 && ns <= MAXS && n >= 1) {
        char* w = (char*)d_ws;
        int*  superCnt = (int*)(w + 0);
        int*  superCB  = (int*)(w + 256);
        int*  superCur = (int*)(w + 512);
        int2* chunkInfo = (int2*)(w + o6_chunk);
        u16*  cellList = (u16*)(w + o6_list);
        int*  strokeCnt = (int*)(w + o6_list + (size_t)NC * MAXS * 2);
        int2* idxTmp   = (int2*)(w + o6_tmp);
        int*  idxFinal = (int*)(w + o6_final);

        hipMemsetAsync(superCnt, 0, 256, stream);
        hipMemsetAsync(chunkInfo, 0xFF, (size_t)maxChunks6 * 8, stream);
        hipMemsetAsync(idxFinal, 0xFF, nslots6 * 4, stream);

        kA<<<(n + 1023) / 1024, 256, 0, stream>>>(coords, out, superCnt, n);
        kB<<<1, 64, 0, stream>>>(superCnt, superCB, superCur);
        kC<<<(n + 2047) / 2048, 256, 0, stream>>>(out, superCur, idxTmp, n);
        kD<<<64, 1024, 0, stream>>>(superCnt, superCB, idxTmp, idxFinal,
                                    chunkInfo, (int*)(w + o6_cellCnt));
        kE<<<(NC * 64 + 255) / 256, 256, 0, stream>>>(shape, cellList, ns);
        kF<<<(maxChunks6 + 3) / 4, 256, 0, stream>>>(
            shape, color, alpha, chunkInfo, idxFinal, cellList, strokeCnt,
            out, n, ns, maxChunks6);
    } else {
        int per_block = 256 * PTS;
        int grid = (n + per_block - 1) / per_block;
        stroke_direct<<<grid, 256, 0, stream>>>(coords, shape, color, alpha, out, n, ns);
    }
}

// Round 2
// 230.922 us; speedup vs baseline: 1.3544x; 1.1726x over previous
//
#include <hip/hip_runtime.h>

// StrokeField R8: chunk=128 (2 pts/lane, dual dep chains), kE folded into kF
// (on-the-fly ballot-compacted stroke list in LDS, uniform-LDS broadcast
// instead of readlane), pipeline 9->7 dispatches (cell histogram in kA,
// fused 1-block kScan replaces kB7+kS7, kC7 loses chist).
// R7 post-mortem: kF7 VALUBusy only 56% -- single dep chain/lane is
// latency-bound (~40cy chain vs ~30cy issue per stroke); kB7/kS7 = two
// 1-block launches serializing the device; kE a separate stage + 4MB buffer.
// Scatter-write amplification (153MB) deliberately untouched this round.

#define NC_DIM 16
#define NC (NC_DIM * NC_DIM * NC_DIM)   // 4096 cells = 64 supercells x 64 sub
#define MAXS 512
#define CELL_INV 8.0f
#define CHK 128                          // points per chunk (2 per lane)

typedef unsigned short u16;
typedef unsigned long long u64;

__device__ __forceinline__ void contract_pt(float x, float y, float z,
                                            float& cx, float& cy, float& cz) {
    float n2 = fmaf(x, x, fmaf(y, y, z * z));
    float nn = fmaxf(__builtin_amdgcn_sqrtf(n2), 1e-9f);
    float invn = 1.0f / nn;
    float scl = (nn <= 1.0f) ? 0.5f : (2.0f - invn) * (0.5f * invn);
    cx = x * scl; cy = y * scl; cz = z * scl;
}

__device__ __forceinline__ int cid_of(float cx, float cy, float cz) {
    int ix = (int)floorf((cx + 1.0f) * CELL_INV);
    int iy = (int)floorf((cy + 1.0f) * CELL_INV);
    int iz = (int)floorf((cz + 1.0f) * CELL_INV);
    ix = min(max(ix, 0), 15); iy = min(max(iy, 0), 15); iz = min(max(iz, 0), 15);
    return ix | (iy << 4) | (iz << 8);
}
__device__ __forceinline__ int sid_of(int cid) {   // supercell 0..63
    return ((cid >> 2) & 3) | (((cid >> 6) & 3) << 2) | (((cid >> 10) & 3) << 4);
}
__device__ __forceinline__ int sub_of(int cid) {   // subcell 0..63
    return (cid & 3) | (((cid >> 4) & 3) << 2) | (((cid >> 8) & 3) << 4);
}
__device__ __forceinline__ int cid_from(int s, int t) {
    int ix = (((s) & 3) << 2) | (t & 3);
    int iy = (((s >> 2) & 3) << 2) | ((t >> 2) & 3);
    int iz = (((s >> 4) & 3) << 2) | ((t >> 4) & 3);
    return ix | (iy << 4) | (iz << 8);
}

// KA: contract, write cw, full 4096-cell histogram (LDS-aggregated).
__global__ __launch_bounds__(256) void kA(
    const float* __restrict__ coords, float* __restrict__ out,
    int* __restrict__ cellCnt, int n)
{
    __shared__ int chist[NC];            // 16KB
    for (int t = threadIdx.x; t < NC; t += 256) chist[t] = 0;
    __syncthreads();
    float* cw = out + 4 * (size_t)n;
    int base = blockIdx.x * 2048 + threadIdx.x;
#pragma unroll
    for (int k = 0; k < 8; ++k) {
        int i = base + k * 256;
        if (i < n) {
            float cx, cy, cz;
            contract_pt(coords[3 * i], coords[3 * i + 1], coords[3 * i + 2], cx, cy, cz);
            cw[3 * i] = cx; cw[3 * i + 1] = cy; cw[3 * i + 2] = cz;
            atomicAdd(&chist[cid_of(cx, cy, cz)], 1);
        }
    }
    __syncthreads();
    for (int t = threadIdx.x; t < NC; t += 256) {
        int v = chist[t];
        if (v) atomicAdd(&cellCnt[t], v);
    }
}

// KScan: one block. Chunk-aligned scan over 4096 cells (supercell-major)
// + element scan over 64 supercells + supercell counts. Replaces kB7+kS7.
__global__ __launch_bounds__(1024) void kScan(
    const int* __restrict__ cellCnt, int* __restrict__ cellCB,
    int* __restrict__ cellCur, int* __restrict__ superBase,
    int* __restrict__ superCur, int* __restrict__ superCnt)
{
    __shared__ int tch[1024], tel[1024];
    int t = threadIdx.x;
    int cids[4], chs[4];
    int chLoc = 0, elLoc = 0;
#pragma unroll
    for (int q = 0; q < 4; ++q) {
        int k = t * 4 + q;                 // supercell-major cell order
        int cid = cid_from(k >> 6, k & 63);
        cids[q] = cid;
        int c = cellCnt[cid];
        chs[q] = (c + CHK - 1) >> 7;
        chLoc += chs[q]; elLoc += c;
    }
    tch[t] = chLoc; tel[t] = elLoc;
    __syncthreads();
    for (int off = 1; off < 1024; off <<= 1) {
        int u1 = (t >= off) ? tch[t - off] : 0;
        int u2 = (t >= off) ? tel[t - off] : 0;
        __syncthreads();
        tch[t] += u1; tel[t] += u2;
        __syncthreads();
    }
    int chEx = tch[t] - chLoc;
    int elEx = tel[t] - elLoc;
#pragma unroll
    for (int q = 0; q < 4; ++q) {
        cellCB[cids[q]] = chEx;
        cellCur[cids[q]] = chEx << 7;      // slot cursor (128-aligned chunks)
        chEx += chs[q];
    }
    if ((t & 15) == 0) { superBase[t >> 4] = elEx; superCur[t >> 4] = elEx; }
    if ((t & 15) == 15) superCnt[t >> 4] = tel[t] - ((t >= 16) ? tel[t - 16] : 0);
}

// KC: block-aggregated scatter of float4(cw, idx|sub<<21) into supercell runs.
__global__ __launch_bounds__(256) void kC(
    const float* __restrict__ out, int* __restrict__ superCur,
    float4* __restrict__ sortedTmp, int n)
{
    __shared__ int scnt[64], sbase[64];
    if (threadIdx.x < 64) scnt[threadIdx.x] = 0;
    __syncthreads();
    const float* cw = out + 4 * (size_t)n;
    int base = blockIdx.x * 2048 + threadIdx.x;
    float cx[8], cy[8], cz[8];
    int cid[8], sid[8];
#pragma unroll
    for (int k = 0; k < 8; ++k) {
        int i = base + k * 256;
        if (i < n) {
            cx[k] = cw[3 * i]; cy[k] = cw[3 * i + 1]; cz[k] = cw[3 * i + 2];
            int c = cid_of(cx[k], cy[k], cz[k]);
            cid[k] = c; sid[k] = sid_of(c);
            atomicAdd(&scnt[sid[k]], 1);
        } else sid[k] = -1;
    }
    __syncthreads();
    if (threadIdx.x < 64) {
        int c = scnt[threadIdx.x];
        sbase[threadIdx.x] = c ? atomicAdd(&superCur[threadIdx.x], c) : 0;
        scnt[threadIdx.x] = 0;
    }
    __syncthreads();
#pragma unroll
    for (int k = 0; k < 8; ++k) {
        if (sid[k] >= 0) {
            int i = base + k * 256;
            int r = atomicAdd(&scnt[sid[k]], 1);
            sortedTmp[sbase[sid[k]] + r] = make_float4(
                cx[k], cy[k], cz[k],
                __int_as_float(i | (sub_of(cid[k]) << 21)));
        }
    }
}

// KD: 4 blocks per supercell (blockIdx = g*64+s keeps all 4 on one XCD),
// forward float4s into 128-aligned cell chunks; g==0 emits chunkInfo.
__global__ __launch_bounds__(1024) void kD(
    const int* __restrict__ superCnt, const int* __restrict__ superBase,
    const float4* __restrict__ sortedTmp, float4* __restrict__ sortedPts,
    int* __restrict__ cellCur, const int* __restrict__ cellCnt,
    const int* __restrict__ cellCB, int2* __restrict__ chunkInfo)
{
    __shared__ int cnt64[64], gbase[64];
    int s = blockIdx.x & 63, g = blockIdx.x >> 6;
    int t = threadIdx.x;
    if (t < 64) cnt64[t] = 0;
    if (g == 0 && t < 64) {
        int cid = cid_from(s, t);
        int c = cellCnt[cid];
        int cb = cellCB[cid];
        int nch = (c + CHK - 1) >> 7;
        for (int q = 0; q < nch; ++q) {
            int rem = c - (q << 7); rem = rem > CHK ? CHK : rem;
            chunkInfo[cb + q] = make_int2(cid | (rem << 16), (cb + q) << 7);
        }
    }
    __syncthreads();
    int cnt = superCnt[s];
    int rb = superBase[s];
    int q0 = (int)(((long long)cnt * g) >> 2);
    int q1 = (int)(((long long)cnt * (g + 1)) >> 2);
    for (int j = q0 + t; j < q1; j += 1024) {
        int bits = __float_as_int(sortedTmp[rb + j].w);
        atomicAdd(&cnt64[(bits >> 21) & 63], 1);
    }
    __syncthreads();
    if (t < 64) {
        int c = cnt64[t];
        gbase[t] = c ? atomicAdd(&cellCur[cid_from(s, t)], c) : 0;
        cnt64[t] = 0;
    }
    __syncthreads();
    for (int j = q0 + t; j < q1; j += 1024) {
        float4 p = sortedTmp[rb + j];
        int bits = __float_as_int(p.w);
        int sub = (bits >> 21) & 63;
        int r = atomicAdd(&cnt64[sub], 1);
        p.w = __int_as_float(bits & 0x1FFFFF);
        sortedPts[gbase[sub] + r] = p;
    }
}

// KF: one wave per 128-pt chunk (2 pts/lane); on-the-fly stroke list
// (ballot-compacted into LDS), uniform-LDS broadcast blend.
__global__ __launch_bounds__(256) void kF(
    const float* __restrict__ shape, const float* __restrict__ color,
    const float* __restrict__ alpha,
    const int2* __restrict__ chunkInfo, const float4* __restrict__ sortedPts,
    float* __restrict__ out, int n, int ns, int maxChunks)
{
    __shared__ float4 sA[MAXS];      // (ax, ay, az, K = 0.5 - 5r)
    __shared__ float4 sB[MAXS];      // (dp, cr, cg, cb)
    __shared__ u16 wl[4][MAXS];      // per-wave stroke sublist
    for (int s = threadIdx.x; s < ns; s += blockDim.x) {
        float4 sp = ((const float4*)shape)[s];
        sA[s] = make_float4(sp.x, sp.y, sp.z, fmaf(-5.0f, sp.w, 0.5f));
        sB[s] = make_float4(fmaxf(alpha[s], 0.0f) * 50.0f,
                            color[3 * s], color[3 * s + 1], color[3 * s + 2]);
    }
    __syncthreads();

    int w = threadIdx.x >> 6, lane = threadIdx.x & 63;
    int k = blockIdx.x * 4 + w;
    if (k >= maxChunks) return;
    int2 info = chunkInfo[k];
    if (info.x < 0) return;
    int cell = info.x & 0xFFF;
    int cnum = info.x >> 16;          // 1..128

    float4 pA = sortedPts[info.y + lane];
    float4 pB = sortedPts[info.y + 64 + lane];
    bool vA = lane < cnum;
    bool vB = lane + 64 < cnum;
    int iA = __float_as_int(pA.w) & 0x1FFFFF;
    int iB = __float_as_int(pB.w) & 0x1FFFFF;
    float xA = vA ? pA.x : 1e9f, yA = vA ? pA.y : 1e9f, zA = vA ? pA.z : 1e9f;
    float xB = vB ? pB.x : 1e9f, yB = vB ? pB.y : 1e9f, zB = vB ? pB.z : 1e9f;

    // Build this cell's ordered stroke sublist (AABB vs sphere, from sA).
    int ix = cell & 15, iy = (cell >> 4) & 15, iz = cell >> 8;
    float lox = -1.0f + ix * 0.125f, hix = lox + 0.125f;
    float loy = -1.0f + iy * 0.125f, hiy = loy + 0.125f;
    float loz = -1.0f + iz * 0.125f, hiz = loz + 0.125f;
    u16* lst = wl[w];
    int nl = 0;
    for (int bs = 0; bs < ns; bs += 64) {
        int s = bs + lane;
        bool pass = false;
        if (s < ns) {
            float4 a = sA[s];
            float dx = a.x - fminf(fmaxf(a.x, lox), hix);
            float dy = a.y - fminf(fmaxf(a.y, loy), hiy);
            float dz = a.z - fminf(fmaxf(a.z, loz), hiz);
            float d2 = fmaf(dx, dx, fmaf(dy, dy, dz * dz));
            float rr = fmaf(-0.2f, a.w, 0.201f);   // r + 0.101
            pass = d2 <= rr * rr;
        }
        u64 m = __ballot(pass);
        if (pass) lst[nl + __popcll(m & ((1ull << lane) - 1ull))] = (u16)s;
        nl += __popcll(m);
    }

    float TA = 1.0f, dA = 0.0f, rA = 0.0f, gA = 0.0f, bA = 0.0f;
    float TB = 1.0f, dB = 0.0f, rB = 0.0f, gB = 0.0f, bB = 0.0f;
    if (nl > 0) {
        int sid = lst[nl - 1];
        float4 a = sA[sid], b = sB[sid];
        for (int j = nl - 1; j >= 0; --j) {
            int sidn = lst[j > 0 ? j - 1 : 0];
            float4 an = sA[sidn], bn = sB[sidn];
            // point A
            float dxA = xA - a.x, dyA = yA - a.y, dzA = zA - a.z;
            float d2A = fmaf(dxA, dxA, fmaf(dyA, dyA, dzA * dzA));
            float omtA = fminf(fmaxf(fmaf(5.0f, __builtin_amdgcn_sqrtf(d2A), a.w), 0.0f), 1.0f);
            float TnA = omtA * TA;
            float tTA = TA - TnA;
            dA = fmaf(tTA, b.x, dA); rA = fmaf(tTA, b.y, rA);
            gA = fmaf(tTA, b.z, gA); bA = fmaf(tTA, b.w, bA);
            TA = TnA;
            // point B
            float dxB = xB - a.x, dyB = yB - a.y, dzB = zB - a.z;
            float d2B = fmaf(dxB, dxB, fmaf(dyB, dyB, dzB * dzB));
            float omtB = fminf(fmaxf(fmaf(5.0f, __builtin_amdgcn_sqrtf(d2B), a.w), 0.0f), 1.0f);
            float TnB = omtB * TB;
            float tTB = TB - TnB;
            dB = fmaf(tTB, b.x, dB); rB = fmaf(tTB, b.y, rB);
            gB = fmaf(tTB, b.z, gB); bB = fmaf(tTB, b.w, bB);
            TB = TnB;
            a = an; b = bn;
        }
    }

    float* rgb = out + n;
    if (vA) {
        float inv = 1.0f / (1.0f + 1e-6f - TA);
        out[iA] = dA;
        rgb[3 * iA]     = fminf(fmaxf(rA * inv, 0.0f), 1.0f);
        rgb[3 * iA + 1] = fminf(fmaxf(gA * inv, 0.0f), 1.0f);
        rgb[3 * iA + 2] = fminf(fmaxf(bA * inv, 0.0f), 1.0f);
    }
    if (vB) {
        float inv = 1.0f / (1.0f + 1e-6f - TB);
        out[iB] = dB;
        rgb[3 * iB]     = fminf(fmaxf(rB * inv, 0.0f), 1.0f);
        rgb[3 * iB + 1] = fminf(fmaxf(gB * inv, 0.0f), 1.0f);
        rgb[3 * iB + 2] = fminf(fmaxf(bB * inv, 0.0f), 1.0f);
    }
}

// ---- Fallback: R4 direct kernel ----
#define PTS 4
__global__ __launch_bounds__(256) void stroke_direct(
    const float* __restrict__ coords, const float* __restrict__ shape,
    const float* __restrict__ color, const float* __restrict__ alpha,
    float* __restrict__ out, int n, int ns)
{
    __shared__ float4 fA[MAXS + 1];
    __shared__ float4 fB[MAXS + 1];
    for (int s = threadIdx.x; s < ns; s += blockDim.x) {
        float4 sp = ((const float4*)shape)[s];
        fA[s + 1] = make_float4(sp.x, sp.y, sp.z, fmaf(-5.0f, sp.w, 0.5f));
        fB[s + 1] = make_float4(fmaxf(alpha[s], 0.0f) * 50.0f,
                                color[3 * s], color[3 * s + 1], color[3 * s + 2]);
    }
    __syncthreads();
    const int base = blockIdx.x * (blockDim.x * PTS) + threadIdx.x;
    float cx[PTS], cy[PTS], cz[PTS], T[PTS], Ad[PTS], Ar[PTS], Ag[PTS], Ab[PTS];
#pragma unroll
    for (int k = 0; k < PTS; ++k) {
        int i = base + k * 256; i = (i < n) ? i : (n - 1);
        contract_pt(coords[3 * i], coords[3 * i + 1], coords[3 * i + 2],
                    cx[k], cy[k], cz[k]);
        T[k] = 1.0f; Ad[k] = Ar[k] = Ag[k] = Ab[k] = 0.0f;
    }
    float4 a = fA[ns], b = fB[ns];
#pragma unroll 2
    for (int s = ns - 1; s >= 0; --s) {
        float4 an = fA[s], bn = fB[s];
#pragma unroll
        for (int k = 0; k < PTS; ++k) {
            float dx = cx[k] - a.x, dy = cy[k] - a.y, dz = cz[k] - a.z;
            float d2 = fmaf(dx, dx, fmaf(dy, dy, dz * dz));
            float dist = __builtin_amdgcn_sqrtf(d2);
            float omt = fminf(fmaxf(fmaf(5.0f, dist, a.w), 0.0f), 1.0f);
            float Tn = omt * T[k];
            float tT = T[k] - Tn;
            Ad[k] = fmaf(tT, b.x, Ad[k]); Ar[k] = fmaf(tT, b.y, Ar[k]);
            Ag[k] = fmaf(tT, b.z, Ag[k]); Ab[k] = fmaf(tT, b.w, Ab[k]);
            T[k] = Tn;
        }
        a = an; b = bn;
    }
    float* rgb = out + n;
    float* cw  = out + 4 * (size_t)n;
#pragma unroll
    for (int k = 0; k < PTS; ++k) {
        int i = base + k * 256;
        if (i >= n) break;
        float inv = 1.0f / (1.0f + 1e-6f - T[k]);
        out[i] = Ad[k];
        rgb[3 * i]     = fminf(fmaxf(Ar[k] * inv, 0.0f), 1.0f);
        rgb[3 * i + 1] = fminf(fmaxf(Ag[k] * inv, 0.0f), 1.0f);
        rgb[3 * i + 2] = fminf(fmaxf(Ab[k] * inv, 0.0f), 1.0f);
        cw[3 * i]     = cx[k];
        cw[3 * i + 1] = cy[k];
        cw[3 * i + 2] = cz[k];
    }
}

extern "C" void kernel_launch(void* const* d_in, const int* in_sizes, int n_in,
                              void* d_out, int out_size, void* d_ws, size_t ws_size,
                              hipStream_t stream) {
    const float* coords = (const float*)d_in[0];
    const float* shape  = (const float*)d_in[1];
    const float* color  = (const float*)d_in[2];
    const float* alpha  = (const float*)d_in[3];
    float* out = (float*)d_out;

    int n  = in_sizes[0] / 3;
    int ns = in_sizes[1] / 4;

    auto al = [](size_t v) { return (v + 255) & ~(size_t)255; };

    int maxChunks = (n + CHK - 1) / CHK + NC;
    size_t o_cellCnt   = 0;                                   // NC*4
    size_t o_cellCB    = (size_t)NC * 4;                      // NC*4
    size_t o_cellCur   = (size_t)NC * 8;                      // NC*4
    size_t o_superBase = (size_t)NC * 12;                     // 256
    size_t o_superCur  = o_superBase + 256;                   // 256
    size_t o_superCnt  = o_superBase + 512;                   // 256
    size_t o_chunk     = al(o_superBase + 768);
    size_t o_tmp       = al(o_chunk + (size_t)maxChunks * 8);
    size_t o_pts       = al(o_tmp + (size_t)n * 16);
    size_t need        = o_pts + (size_t)maxChunks * CHK * 16;

    if (ws_size >= need && ns <= MAXS && n >= 1 && n <= (1 << 21)) {
        char* w = (char*)d_ws;
        int*    cellCnt   = (int*)(w + o_cellCnt);
        int*    cellCB    = (int*)(w + o_cellCB);
        int*    cellCur   = (int*)(w + o_cellCur);
        int*    superBase = (int*)(w + o_superBase);
        int*    superCur  = (int*)(w + o_superCur);
        int*    superCnt  = (int*)(w + o_superCnt);
        int2*   chunkInfo = (int2*)(w + o_chunk);
        float4* sortedTmp = (float4*)(w + o_tmp);
        float4* sortedPts = (float4*)(w + o_pts);

        hipMemsetAsync(cellCnt, 0, (size_t)NC * 4, stream);
        hipMemsetAsync(chunkInfo, 0xFF, (size_t)maxChunks * 8, stream);

        kA<<<(n + 2047) / 2048, 256, 0, stream>>>(coords, out, cellCnt, n);
        kScan<<<1, 1024, 0, stream>>>(cellCnt, cellCB, cellCur,
                                      superBase, superCur, superCnt);
        kC<<<(n + 2047) / 2048, 256, 0, stream>>>(out, superCur, sortedTmp, n);
        kD<<<256, 1024, 0, stream>>>(superCnt, superBase, sortedTmp, sortedPts,
                                     cellCur, cellCnt, cellCB, chunkInfo);
        kF<<<(maxChunks + 3) / 4, 256, 0, stream>>>(
            shape, color, alpha, chunkInfo, sortedPts, out, n, ns, maxChunks);
    } else {
        int per_block = 256 * PTS;
        int grid = (n + per_block - 1) / per_block;
        stroke_direct<<<grid, 256, 0, stream>>>(coords, shape, color, alpha, out, n, ns);
    }
}